// Round 6
// baseline (644.759 us; speedup 1.0000x reference)
//
#include <hip/hip_runtime.h>
#include <hip/hip_bf16.h>

#define T_SEQ 1024

__device__ __forceinline__ float fast_sigmoid(float x) {
    return 1.0f / (1.0f + __expf(-x));
}
__device__ __forceinline__ float fast_tanh(float x) {
    float e = __expf(2.0f * x);
    return 1.0f - 2.0f / (e + 1.0f);
}

// K1: precompute u-dependent parts of both RNN linears (+bias)
__global__ __launch_bounds__(256) void k_rnn_pre(
    const float* __restrict__ u,
    const float* __restrict__ i2h_w, const float* __restrict__ i2h_b,
    const float* __restrict__ h2o_w, const float* __restrict__ h2o_b,
    float* __restrict__ pre_i, float* __restrict__ pre_o) {
    int idx = blockIdx.x * 256 + threadIdx.x;   // 0..65535
    int k = idx >> 6, i = idx & 63;
    float a = i2h_b[i], b = h2o_b[i];
#pragma unroll
    for (int c = 0; c < 8; ++c) {
        float uv = u[k * 8 + c];
        a += uv * i2h_w[i * 72 + c];
        b += uv * h2o_w[i * 72 + c];
    }
    pre_i[idx] = a;
    pre_o[idx] = b;
}

// K2: serial h-chain, ONE wave, ping-pong h buffers, 1 barrier/step.
// pre_i prefetched through a depth-4 register FIFO (p0..p3, loop unrolled x4,
// all-static names per rule #20) so the ~600-900cy L3/HBM latency is hidden
// under ~3 full steps of compute instead of <1 (the round-5 exposure).
#define CHAIN_STEP(PF, KIDX)                                                   \
    {                                                                          \
        const float4* h4 = reinterpret_cast<const float4*>(hbuf[(KIDX) & 1]);  \
        float pcur = PF;                                                       \
        int kk = (KIDX) + 4; if (kk > T_SEQ - 1) kk = T_SEQ - 1;               \
        PF = pre_i[kk * 64 + i];  /* consumed 4 steps from now */              \
        float a0 = 0.0f, a1 = 0.0f, a2 = 0.0f, a3 = 0.0f;                      \
        _Pragma("unroll")                                                      \
        for (int v = 0; v < 16; v += 4) {                                      \
            float4 x0 = h4[v], x1 = h4[v + 1], x2 = h4[v + 2], x3 = h4[v + 3]; \
            a0 += wr[4*v+ 0]*x0.x + wr[4*v+ 1]*x0.y + wr[4*v+ 2]*x0.z + wr[4*v+ 3]*x0.w; \
            a1 += wr[4*v+ 4]*x1.x + wr[4*v+ 5]*x1.y + wr[4*v+ 6]*x1.z + wr[4*v+ 7]*x1.w; \
            a2 += wr[4*v+ 8]*x2.x + wr[4*v+ 9]*x2.y + wr[4*v+10]*x2.z + wr[4*v+11]*x2.w; \
            a3 += wr[4*v+12]*x3.x + wr[4*v+13]*x3.y + wr[4*v+14]*x3.z + wr[4*v+15]*x3.w; \
        }                                                                      \
        float hn = fast_tanh(((a0 + a1) + (a2 + a3)) + pcur);                  \
        hbuf[((KIDX) & 1) ^ 1][i] = hn;                                        \
        /* KIDX=1023 writes hseq[1024*64+..] = uo[0..63]: overwritten by */    \
        /* k_rnn_out before k_batch reads uo (stream-ordered, benign).   */    \
        hseq[((KIDX) + 1) * 64 + i] = hn;                                      \
        __syncthreads();                                                       \
    }

__global__ __launch_bounds__(64) void k_rnn_chain(
    const float* __restrict__ i2h_w,
    const float* __restrict__ pre_i,
    float* __restrict__ hseq) {
    __shared__ float hbuf[2][64];
    const int i = threadIdx.x;
    float wr[64];
#pragma unroll
    for (int j = 0; j < 64; ++j) wr[j] = i2h_w[i * 72 + 8 + j];
    hbuf[0][i] = 0.0f;
    hseq[i] = 0.0f;                       // hseq[0] = h before step 0
    float p0 = pre_i[0 * 64 + i];
    float p1 = pre_i[1 * 64 + i];
    float p2 = pre_i[2 * 64 + i];
    float p3 = pre_i[3 * 64 + i];
    __syncthreads();
    for (int k = 0; k < T_SEQ; k += 4) {
        CHAIN_STEP(p0, k)
        CHAIN_STEP(p1, k + 1)
        CHAIN_STEP(p2, k + 2)
        CHAIN_STEP(p3, k + 3)
    }
}

// K3: all RNN outputs in parallel
__global__ __launch_bounds__(64) void k_rnn_out(
    const float* __restrict__ h2o_w,
    const float* __restrict__ pre_o,
    const float* __restrict__ hseq,
    float* __restrict__ uout) {
    int k = blockIdx.x, i = threadIdx.x;
    __shared__ float hk[64];
    hk[i] = hseq[k * 64 + i];
    __syncthreads();
    float acc = pre_o[k * 64 + i];
#pragma unroll
    for (int m = 0; m < 64; ++m) acc += h2o_w[i * 72 + 8 + m] * hk[m];
    uout[k * 64 + i] = fast_tanh(acc);
}

// ---- packed weight block layout (floats), produced by k_repack, copied to LDS ----
#define L_XW1 0       // 20 rows of 68: {w_t,pad,pad,pad, w_x0..63}
#define L_UW1 1360
#define L_XW2 2720    // 20 rows of 20 (80B rows, 16B-aligned)
#define L_UW2 3120
#define L_XW3 3520    // 64 rows of 20
#define L_UW3 4800
#define L_CWT 6080    // cwT[128][64]: cwT[j][s] = cw[s*128+j]
#define L_XB1 14272
#define L_XB2 14292
#define L_UB1 14312
#define L_UB2 14332
#define L_XB3 14352
#define L_UB3 14416
#define L_CB  14480
#define L_TOT 14544   // 58176 bytes

__global__ __launch_bounds__(256) void k_repack(
    const float* __restrict__ xw1, const float* __restrict__ uw1,
    const float* __restrict__ xw2, const float* __restrict__ uw2,
    const float* __restrict__ xw3, const float* __restrict__ uw3,
    const float* __restrict__ cw,
    const float* __restrict__ xb1, const float* __restrict__ xb2,
    const float* __restrict__ ub1, const float* __restrict__ ub2,
    const float* __restrict__ xb3, const float* __restrict__ ub3,
    const float* __restrict__ cb, float* __restrict__ wp) {
    int i = blockIdx.x * 256 + threadIdx.x;
    if (i >= L_TOT) return;
    float v = 0.0f;
    if (i < 1360) {
        int o = i / 68, c = i - o * 68;
        if (c == 0) v = xw1[o * 65];
        else if (c >= 4) v = xw1[o * 65 + c - 3];
    } else if (i < 2720) {
        int j = i - 1360; int o = j / 68, c = j - o * 68;
        if (c == 0) v = uw1[o * 65];
        else if (c >= 4) v = uw1[o * 65 + c - 3];
    } else if (i < 3120) v = xw2[i - 2720];
    else if (i < 3520) v = uw2[i - 3120];
    else if (i < 4800) v = xw3[i - 3520];
    else if (i < 6080) v = uw3[i - 4800];
    else if (i < 14272) {
        int j = i - 6080; int row = j >> 6, s = j & 63;
        v = cw[s * 128 + row];
    }
    else if (i < 14292) v = xb1[i - 14272];
    else if (i < 14312) v = xb2[i - 14292];
    else if (i < 14332) v = ub1[i - 14312];
    else if (i < 14352) v = ub2[i - 14332];
    else if (i < 14416) v = xb3[i - 14352];
    else if (i < 14480) v = ub3[i - 14416];
    else v = cb[i - 14480];
    wp[i] = v;
}

// ---- K4: fused batch kernel, ONE row/thread, LDS weights, b128 broadcasts ----
template <int OW1, int OB1, int OW2, int OB2>
__device__ __forceinline__ void mlp20(const float* __restrict__ sm,
                                      float tval, const float4* z, float* h2) {
    float h1[20];
#pragma unroll 4
    for (int o = 0; o < 20; ++o) {
        const int ro = OW1 + o * 68;
        float a = sm[OB1 + o] + tval * sm[ro];
        const float4* wr = reinterpret_cast<const float4*>(&sm[ro + 4]);
#pragma unroll
        for (int v = 0; v < 16; ++v) {
            float4 w4 = wr[v];
            a += z[v].x * w4.x + z[v].y * w4.y + z[v].z * w4.z + z[v].w * w4.w;
        }
        h1[o] = fast_sigmoid(a);
    }
#pragma unroll 4
    for (int o = 0; o < 20; ++o) {
        float a = sm[OB2 + o];
        const float4* wr = reinterpret_cast<const float4*>(&sm[OW2 + o * 20]);
#pragma unroll
        for (int v = 0; v < 5; ++v) {
            float4 w4 = wr[v];
            a += h1[4*v+0]*w4.x + h1[4*v+1]*w4.y + h1[4*v+2]*w4.z + h1[4*v+3]*w4.w;
        }
        h2[o] = fast_sigmoid(a);
    }
}

template <int OW3, int OB3, int OCWT>
__device__ __forceinline__ void final64(const float* __restrict__ sm,
                                        const float* h2, float* oacc) {
#pragma unroll 2
    for (int o = 0; o < 64; ++o) {
        float a = sm[OB3 + o];
        const float4* wr = reinterpret_cast<const float4*>(&sm[OW3 + o * 20]);
#pragma unroll
        for (int v = 0; v < 5; ++v) {
            float4 w4 = wr[v];
            a += h2[4*v+0]*w4.x + h2[4*v+1]*w4.y + h2[4*v+2]*w4.z + h2[4*v+3]*w4.w;
        }
        float s = fast_sigmoid(a);
        const float4* cr = reinterpret_cast<const float4*>(&sm[OCWT + o * 64]);
#pragma unroll
        for (int v = 0; v < 16; ++v) {
            float4 c4 = cr[v];
            oacc[4*v+0] += s * c4.x; oacc[4*v+1] += s * c4.y;
            oacc[4*v+2] += s * c4.z; oacc[4*v+3] += s * c4.w;
        }
    }
}

__global__ __launch_bounds__(256) void k_batch(
    const float* __restrict__ t_in, const float* __restrict__ x_in,
    const float* __restrict__ uo, const float* __restrict__ wp,
    float* __restrict__ out) {
    __shared__ float sm[L_TOT];
    const int tid = threadIdx.x;
    {   // straight float4 copy of the packed weight block (conflict-free, coalesced)
        float4* s4 = reinterpret_cast<float4*>(sm);
        const float4* w4 = reinterpret_cast<const float4*>(wp);
        for (int idx = tid; idx < L_TOT / 4; idx += 256) s4[idx] = w4[idx];
    }
    __syncthreads();

    const int r = blockIdx.x * 256 + tid;
    float tval = t_in[r];
    float4 z[16];
    const float4* xp = reinterpret_cast<const float4*>(x_in + (size_t)r * 64);
#pragma unroll
    for (int v = 0; v < 16; ++v) z[v] = xp[v];

    // state branch fully, then retire z before loading control input
    float h2[20];
    mlp20<L_XW1, L_XB1, L_XW2, L_XB2>(sm, tval, z, h2);

    float oacc[64];
    {
        const float4* cbp = reinterpret_cast<const float4*>(&sm[L_CB]);
#pragma unroll
        for (int v = 0; v < 16; ++v) {
            float4 c4 = cbp[v];
            oacc[4*v+0] = c4.x; oacc[4*v+1] = c4.y;
            oacc[4*v+2] = c4.z; oacc[4*v+3] = c4.w;
        }
    }
    final64<L_XW3, L_XB3, L_CWT>(sm, h2, oacc);

    // control branch
    int ti = min((int)(tval * 1024.0f), 1023);
    const float4* ep = reinterpret_cast<const float4*>(uo + ti * 64);
#pragma unroll
    for (int v = 0; v < 16; ++v) z[v] = ep[v];
    mlp20<L_UW1, L_UB1, L_UW2, L_UB2>(sm, tval, z, h2);
    final64<L_UW3, L_UB3, L_CWT + 64 * 64>(sm, h2, oacc);

    float4* op = reinterpret_cast<float4*>(out + (size_t)r * 64);
#pragma unroll
    for (int v = 0; v < 16; ++v) {
        float4 f;
        f.x = oacc[4*v+0]; f.y = oacc[4*v+1];
        f.z = oacc[4*v+2]; f.w = oacc[4*v+3];
        op[v] = f;
    }
}

extern "C" void kernel_launch(void* const* d_in, const int* in_sizes, int n_in,
                              void* d_out, int out_size, void* d_ws, size_t ws_size,
                              hipStream_t stream) {
    const float* t     = (const float*)d_in[0];
    const float* x     = (const float*)d_in[1];
    const float* u     = (const float*)d_in[2];
    const float* i2h_w = (const float*)d_in[3];
    const float* i2h_b = (const float*)d_in[4];
    const float* h2o_w = (const float*)d_in[5];
    const float* h2o_b = (const float*)d_in[6];
    const float* xw1 = (const float*)d_in[7];  const float* xb1 = (const float*)d_in[8];
    const float* xw2 = (const float*)d_in[9];  const float* xb2 = (const float*)d_in[10];
    const float* xw3 = (const float*)d_in[11]; const float* xb3 = (const float*)d_in[12];
    const float* uw1 = (const float*)d_in[13]; const float* ub1 = (const float*)d_in[14];
    const float* uw2 = (const float*)d_in[15]; const float* ub2 = (const float*)d_in[16];
    const float* uw3 = (const float*)d_in[17]; const float* ub3 = (const float*)d_in[18];
    const float* cw  = (const float*)d_in[19]; const float* cb  = (const float*)d_in[20];
    float* out = (float*)d_out;

    float* ws    = (float*)d_ws;
    float* pre_i = ws;                 // [0,65536)  dead after chain
    float* pre_o = ws + 65536;         // dead after k_rnn_out
    float* hseq  = ws + 131072;        // dead after k_rnn_out
    float* uo    = ws + 196608;        // used by k_batch
    float* wp    = ws;                 // packed weights alias pre_i AFTER chain

    int Bv = in_sizes[0];              // 262144

    hipLaunchKernelGGL(k_rnn_pre, dim3(256), dim3(256), 0, stream,
                       u, i2h_w, i2h_b, h2o_w, h2o_b, pre_i, pre_o);
    hipLaunchKernelGGL(k_rnn_chain, dim3(1), dim3(64), 0, stream,
                       i2h_w, pre_i, hseq);
    hipLaunchKernelGGL(k_rnn_out, dim3(T_SEQ), dim3(64), 0, stream,
                       h2o_w, pre_o, hseq, uo);
    hipLaunchKernelGGL(k_repack, dim3((L_TOT + 255) / 256), dim3(256), 0, stream,
                       xw1, uw1, xw2, uw2, xw3, uw3, cw,
                       xb1, xb2, ub1, ub2, xb3, ub3, cb, wp);
    hipLaunchKernelGGL(k_batch, dim3(Bv / 256), dim3(256), 0, stream,
                       t, x, uo, wp, out);
}

// Round 7
// 549.296 us; speedup vs baseline: 1.1738x; 1.1738x over previous
//
#include <hip/hip_runtime.h>
#include <hip/hip_bf16.h>

#define T_SEQ 1024
#define CHUNK 64                 // steps per chunk
#define NCHUNK (T_SEQ / CHUNK)   // 16

__device__ __forceinline__ float fast_sigmoid(float x) {
    return 1.0f / (1.0f + __expf(-x));
}
__device__ __forceinline__ float fast_tanh(float x) {
    float e = __expf(2.0f * x);
    return 1.0f - 2.0f / (e + 1.0f);
}

// K1: precompute u-dependent parts of both RNN linears (+bias)
__global__ __launch_bounds__(256) void k_rnn_pre(
    const float* __restrict__ u,
    const float* __restrict__ i2h_w, const float* __restrict__ i2h_b,
    const float* __restrict__ h2o_w, const float* __restrict__ h2o_b,
    float* __restrict__ pre_i, float* __restrict__ pre_o) {
    int idx = blockIdx.x * 256 + threadIdx.x;   // 0..65535
    int k = idx >> 6, i = idx & 63;
    float a = i2h_b[i], b = h2o_b[i];
#pragma unroll
    for (int c = 0; c < 8; ++c) {
        float uv = u[k * 8 + c];
        a += uv * i2h_w[i * 72 + c];
        b += uv * h2o_w[i * 72 + c];
    }
    pre_i[idx] = a;
    pre_o[idx] = b;
}

// K2: serial h-chain, producer-consumer wave specialization.
// Wave 0: pure-LDS serial chain (no global ops -> no vmcnt drains, no barriers
// inside a chunk). Wave 1: stages pre_i chunks into LDS and flushes h chunks
// to global, double-buffered, one __syncthreads per chunk (matched counts).
__global__ __launch_bounds__(128) void k_rnn_chain(
    const float* __restrict__ i2h_w,
    const float* __restrict__ pre_i,
    float* __restrict__ hseq) {
    __shared__ float pre_lds[2][CHUNK * 64];   // 2 x 16 KB
    __shared__ float hs_lds[2][CHUNK * 64];    // 2 x 16 KB; hs[b][s*64+i] = h AFTER local step s
    const int tid = threadIdx.x;
    const int lane = tid & 63;
    const int wv = tid >> 6;

    if (wv == 0) {
        // ---- serial chain wave ----
        float2 wr2[32];
#pragma unroll
        for (int m = 0; m < 32; ++m) {
            wr2[m].x = i2h_w[lane * 72 + 8 + 2 * m];
            wr2[m].y = i2h_w[lane * 72 + 8 + 2 * m + 1];
        }
        __syncthreads();                       // B0: chunk 0 staged, h-entry zeroed
        for (int c = 0; c < NCHUNK; ++c) {
            const int cb = c & 1;
            const float* __restrict__ pb = pre_lds[cb];
            float* __restrict__ hw = hs_lds[cb];
            const float* hsrc = &hs_lds[cb ^ 1][(CHUNK - 1) * 64];  // h entering chunk
#pragma unroll 2
            for (int s = 0; s < CHUNK; ++s) {
                const float4* h4 = reinterpret_cast<const float4*>(hsrc);
                float2 a0 = {0.f, 0.f}, a1 = {0.f, 0.f}, a2 = {0.f, 0.f}, a3 = {0.f, 0.f};
#pragma unroll
                for (int v = 0; v < 16; v += 4) {
                    float4 x0 = h4[v], x1 = h4[v + 1], x2 = h4[v + 2], x3 = h4[v + 3];
                    a0.x += wr2[2*v+0].x * x0.x; a0.y += wr2[2*v+0].y * x0.y;
                    a1.x += wr2[2*v+1].x * x0.z; a1.y += wr2[2*v+1].y * x0.w;
                    a2.x += wr2[2*v+2].x * x1.x; a2.y += wr2[2*v+2].y * x1.y;
                    a3.x += wr2[2*v+3].x * x1.z; a3.y += wr2[2*v+3].y * x1.w;
                    a0.x += wr2[2*v+4].x * x2.x; a0.y += wr2[2*v+4].y * x2.y;
                    a1.x += wr2[2*v+5].x * x2.z; a1.y += wr2[2*v+5].y * x2.w;
                    a2.x += wr2[2*v+6].x * x3.x; a2.y += wr2[2*v+6].y * x3.y;
                    a3.x += wr2[2*v+7].x * x3.z; a3.y += wr2[2*v+7].y * x3.w;
                }
                float acc = ((a0.x + a0.y) + (a1.x + a1.y))
                          + ((a2.x + a2.y) + (a3.x + a3.y));
                float hn = fast_tanh(acc + pb[s * 64 + lane]);
                hw[s * 64 + lane] = hn;
                hsrc = &hw[s * 64];
            }
            __syncthreads();                   // chunk c done; stager may flush it
        }
    } else {
        // ---- stager wave ----
        // initial: chunk 0 of pre_i -> pre_lds[0]; zero h-entry; hseq[0]=0
#pragma unroll
        for (int it = 0; it < CHUNK / 4; ++it) {
            float4 v = reinterpret_cast<const float4*>(pre_i)[it * 64 + lane];
            reinterpret_cast<float4*>(pre_lds[0])[it * 64 + lane] = v;
        }
        hs_lds[1][(CHUNK - 1) * 64 + lane] = 0.0f;
        hseq[lane] = 0.0f;                     // hseq[0] = h before step 0
        __syncthreads();                       // B0
        for (int c = 0; c < NCHUNK; ++c) {
            if (c + 1 < NCHUNK) {              // load chunk c+1
                const float4* src = reinterpret_cast<const float4*>(pre_i + (c + 1) * CHUNK * 64);
                float4* dst = reinterpret_cast<float4*>(pre_lds[(c + 1) & 1]);
#pragma unroll
                for (int it = 0; it < CHUNK / 4; ++it) dst[it * 64 + lane] = src[it * 64 + lane];
            }
            if (c >= 1) {                      // flush chunk c-1's h values
                // h after global step k goes to hseq[k+1]
                const float4* src = reinterpret_cast<const float4*>(hs_lds[(c - 1) & 1]);
                float4* dst = reinterpret_cast<float4*>(hseq + ((c - 1) * CHUNK + 1) * 64);
#pragma unroll
                for (int it = 0; it < CHUNK / 4; ++it) dst[it * 64 + lane] = src[it * 64 + lane];
            }
            __syncthreads();                   // matches wave0's chunk barrier
        }
        {   // epilogue: flush final chunk (writes hseq[961..1024]; vector 1024
            // lands in uo[0..63], overwritten by k_rnn_out before k_batch)
            const float4* src = reinterpret_cast<const float4*>(hs_lds[(NCHUNK - 1) & 1]);
            float4* dst = reinterpret_cast<float4*>(hseq + ((NCHUNK - 1) * CHUNK + 1) * 64);
#pragma unroll
            for (int it = 0; it < CHUNK / 4; ++it) dst[it * 64 + lane] = src[it * 64 + lane];
        }
    }
}

// K3: all RNN outputs in parallel
__global__ __launch_bounds__(64) void k_rnn_out(
    const float* __restrict__ h2o_w,
    const float* __restrict__ pre_o,
    const float* __restrict__ hseq,
    float* __restrict__ uout) {
    int k = blockIdx.x, i = threadIdx.x;
    __shared__ float hk[64];
    hk[i] = hseq[k * 64 + i];
    __syncthreads();
    float acc = pre_o[k * 64 + i];
#pragma unroll
    for (int m = 0; m < 64; ++m) acc += h2o_w[i * 72 + 8 + m] * hk[m];
    uout[k * 64 + i] = fast_tanh(acc);
}

// ---- packed weight block layout (floats), produced by k_repack, copied to LDS ----
#define L_XW1 0       // 20 rows of 68: {w_t,pad,pad,pad, w_x0..63}
#define L_UW1 1360
#define L_XW2 2720    // 20 rows of 20 (80B rows, 16B-aligned)
#define L_UW2 3120
#define L_XW3 3520    // 64 rows of 20
#define L_UW3 4800
#define L_CWT 6080    // cwT[128][64]: cwT[j][s] = cw[s*128+j]
#define L_XB1 14272
#define L_XB2 14292
#define L_UB1 14312
#define L_UB2 14332
#define L_XB3 14352
#define L_UB3 14416
#define L_CB  14480
#define L_TOT 14544   // 58176 bytes

__global__ __launch_bounds__(256) void k_repack(
    const float* __restrict__ xw1, const float* __restrict__ uw1,
    const float* __restrict__ xw2, const float* __restrict__ uw2,
    const float* __restrict__ xw3, const float* __restrict__ uw3,
    const float* __restrict__ cw,
    const float* __restrict__ xb1, const float* __restrict__ xb2,
    const float* __restrict__ ub1, const float* __restrict__ ub2,
    const float* __restrict__ xb3, const float* __restrict__ ub3,
    const float* __restrict__ cb, float* __restrict__ wp) {
    int i = blockIdx.x * 256 + threadIdx.x;
    if (i >= L_TOT) return;
    float v = 0.0f;
    if (i < 1360) {
        int o = i / 68, c = i - o * 68;
        if (c == 0) v = xw1[o * 65];
        else if (c >= 4) v = xw1[o * 65 + c - 3];
    } else if (i < 2720) {
        int j = i - 1360; int o = j / 68, c = j - o * 68;
        if (c == 0) v = uw1[o * 65];
        else if (c >= 4) v = uw1[o * 65 + c - 3];
    } else if (i < 3120) v = xw2[i - 2720];
    else if (i < 3520) v = uw2[i - 3120];
    else if (i < 4800) v = xw3[i - 3520];
    else if (i < 6080) v = uw3[i - 4800];
    else if (i < 14272) {
        int j = i - 6080; int row = j >> 6, s = j & 63;
        v = cw[s * 128 + row];
    }
    else if (i < 14292) v = xb1[i - 14272];
    else if (i < 14312) v = xb2[i - 14292];
    else if (i < 14332) v = ub1[i - 14312];
    else if (i < 14352) v = ub2[i - 14332];
    else if (i < 14416) v = xb3[i - 14352];
    else if (i < 14480) v = ub3[i - 14416];
    else v = cb[i - 14480];
    wp[i] = v;
}

// ---- K4: fused batch kernel, ONE row/thread, LDS weights, b128 broadcasts ----
template <int OW1, int OB1, int OW2, int OB2>
__device__ __forceinline__ void mlp20(const float* __restrict__ sm,
                                      float tval, const float4* z, float* h2) {
    float h1[20];
#pragma unroll 4
    for (int o = 0; o < 20; ++o) {
        const int ro = OW1 + o * 68;
        float a = sm[OB1 + o] + tval * sm[ro];
        const float4* wr = reinterpret_cast<const float4*>(&sm[ro + 4]);
#pragma unroll
        for (int v = 0; v < 16; ++v) {
            float4 w4 = wr[v];
            a += z[v].x * w4.x + z[v].y * w4.y + z[v].z * w4.z + z[v].w * w4.w;
        }
        h1[o] = fast_sigmoid(a);
    }
#pragma unroll 4
    for (int o = 0; o < 20; ++o) {
        float a = sm[OB2 + o];
        const float4* wr = reinterpret_cast<const float4*>(&sm[OW2 + o * 20]);
#pragma unroll
        for (int v = 0; v < 5; ++v) {
            float4 w4 = wr[v];
            a += h1[4*v+0]*w4.x + h1[4*v+1]*w4.y + h1[4*v+2]*w4.z + h1[4*v+3]*w4.w;
        }
        h2[o] = fast_sigmoid(a);
    }
}

template <int OW3, int OB3, int OCWT>
__device__ __forceinline__ void final64(const float* __restrict__ sm,
                                        const float* h2, float* oacc) {
#pragma unroll 2
    for (int o = 0; o < 64; ++o) {
        float a = sm[OB3 + o];
        const float4* wr = reinterpret_cast<const float4*>(&sm[OW3 + o * 20]);
#pragma unroll
        for (int v = 0; v < 5; ++v) {
            float4 w4 = wr[v];
            a += h2[4*v+0]*w4.x + h2[4*v+1]*w4.y + h2[4*v+2]*w4.z + h2[4*v+3]*w4.w;
        }
        float s = fast_sigmoid(a);
        const float4* cr = reinterpret_cast<const float4*>(&sm[OCWT + o * 64]);
#pragma unroll
        for (int v = 0; v < 16; ++v) {
            float4 c4 = cr[v];
            oacc[4*v+0] += s * c4.x; oacc[4*v+1] += s * c4.y;
            oacc[4*v+2] += s * c4.z; oacc[4*v+3] += s * c4.w;
        }
    }
}

__global__ __launch_bounds__(256) void k_batch(
    const float* __restrict__ t_in, const float* __restrict__ x_in,
    const float* __restrict__ uo, const float* __restrict__ wp,
    float* __restrict__ out) {
    __shared__ float sm[L_TOT];
    const int tid = threadIdx.x;
    {   // straight float4 copy of the packed weight block (conflict-free, coalesced)
        float4* s4 = reinterpret_cast<float4*>(sm);
        const float4* w4 = reinterpret_cast<const float4*>(wp);
        for (int idx = tid; idx < L_TOT / 4; idx += 256) s4[idx] = w4[idx];
    }
    __syncthreads();

    const int r = blockIdx.x * 256 + tid;
    float tval = t_in[r];
    float4 z[16];
    const float4* xp = reinterpret_cast<const float4*>(x_in + (size_t)r * 64);
#pragma unroll
    for (int v = 0; v < 16; ++v) z[v] = xp[v];

    // state branch fully, then retire z before loading control input
    float h2[20];
    mlp20<L_XW1, L_XB1, L_XW2, L_XB2>(sm, tval, z, h2);

    float oacc[64];
    {
        const float4* cbp = reinterpret_cast<const float4*>(&sm[L_CB]);
#pragma unroll
        for (int v = 0; v < 16; ++v) {
            float4 c4 = cbp[v];
            oacc[4*v+0] = c4.x; oacc[4*v+1] = c4.y;
            oacc[4*v+2] = c4.z; oacc[4*v+3] = c4.w;
        }
    }
    final64<L_XW3, L_XB3, L_CWT>(sm, h2, oacc);

    // control branch
    int ti = min((int)(tval * 1024.0f), 1023);
    const float4* ep = reinterpret_cast<const float4*>(uo + ti * 64);
#pragma unroll
    for (int v = 0; v < 16; ++v) z[v] = ep[v];
    mlp20<L_UW1, L_UB1, L_UW2, L_UB2>(sm, tval, z, h2);
    final64<L_UW3, L_UB3, L_CWT + 64 * 64>(sm, h2, oacc);

    float4* op = reinterpret_cast<float4*>(out + (size_t)r * 64);
#pragma unroll
    for (int v = 0; v < 16; ++v) {
        float4 f;
        f.x = oacc[4*v+0]; f.y = oacc[4*v+1];
        f.z = oacc[4*v+2]; f.w = oacc[4*v+3];
        op[v] = f;
    }
}

extern "C" void kernel_launch(void* const* d_in, const int* in_sizes, int n_in,
                              void* d_out, int out_size, void* d_ws, size_t ws_size,
                              hipStream_t stream) {
    const float* t     = (const float*)d_in[0];
    const float* x     = (const float*)d_in[1];
    const float* u     = (const float*)d_in[2];
    const float* i2h_w = (const float*)d_in[3];
    const float* i2h_b = (const float*)d_in[4];
    const float* h2o_w = (const float*)d_in[5];
    const float* h2o_b = (const float*)d_in[6];
    const float* xw1 = (const float*)d_in[7];  const float* xb1 = (const float*)d_in[8];
    const float* xw2 = (const float*)d_in[9];  const float* xb2 = (const float*)d_in[10];
    const float* xw3 = (const float*)d_in[11]; const float* xb3 = (const float*)d_in[12];
    const float* uw1 = (const float*)d_in[13]; const float* ub1 = (const float*)d_in[14];
    const float* uw2 = (const float*)d_in[15]; const float* ub2 = (const float*)d_in[16];
    const float* uw3 = (const float*)d_in[17]; const float* ub3 = (const float*)d_in[18];
    const float* cw  = (const float*)d_in[19]; const float* cb  = (const float*)d_in[20];
    float* out = (float*)d_out;

    float* ws    = (float*)d_ws;
    float* pre_i = ws;                 // [0,65536)  dead after chain
    float* pre_o = ws + 65536;         // dead after k_rnn_out
    float* hseq  = ws + 131072;        // dead after k_rnn_out
    float* uo    = ws + 196608;        // used by k_batch
    float* wp    = ws;                 // packed weights alias pre_i AFTER chain

    int Bv = in_sizes[0];              // 262144

    hipLaunchKernelGGL(k_rnn_pre, dim3(256), dim3(256), 0, stream,
                       u, i2h_w, i2h_b, h2o_w, h2o_b, pre_i, pre_o);
    hipLaunchKernelGGL(k_rnn_chain, dim3(1), dim3(128), 0, stream,
                       i2h_w, pre_i, hseq);
    hipLaunchKernelGGL(k_rnn_out, dim3(T_SEQ), dim3(64), 0, stream,
                       h2o_w, pre_o, hseq, uo);
    hipLaunchKernelGGL(k_repack, dim3((L_TOT + 255) / 256), dim3(256), 0, stream,
                       xw1, uw1, xw2, uw2, xw3, uw3, cw,
                       xb1, xb2, ub1, ub2, xb3, ub3, cb, wp);
    hipLaunchKernelGGL(k_batch, dim3(Bv / 256), dim3(256), 0, stream,
                       t, x, uo, wp, out);
}